// Round 5
// baseline (1326.313 us; speedup 1.0000x reference)
//
#include <hip/hip_runtime.h>
#include <math.h>

#define WIDTH 256
#define PTS 16             // points per GROUP (two groups per block)
#define NROW 80            // 5 chains * 16 points
#define CPLANE 20480       // halves per component plane: 5v * 8kc * 64lane * 8

typedef _Float16 f16x8 __attribute__((ext_vector_type(8)));
typedef _Float16 f16x4 __attribute__((ext_vector_type(4)));
typedef __fp16   h16x2 __attribute__((ext_vector_type(2)));   // cvt_pkrtz return type
typedef float    f32x4 __attribute__((ext_vector_type(4)));

// fp32 -> fp16 hi + fp16 lo (2-split, covers ~22-24 mantissa bits)
__device__ __forceinline__ void split2(float f, _Float16& h, _Float16& l) {
    h = (_Float16)f;
    l = (_Float16)(f - (float)h);
}
// z=tanh(u), s=1-z^2 = 4t/(1+t)^2 with t=exp(-2|u|): no cancellation in saturation.
// rcp via v_rcp_f32 (~1 ulp) instead of IEEE divide; verified absmax-neutral (r2).
__device__ __forceinline__ void tanh_s(float u, float& z, float& s) {
    const float t = __expf(-2.0f * fabsf(u));
    const float r = __builtin_amdgcn_rcpf(1.0f + t);
    const float zm = (1.0f - t) * r;
    z = copysignf(zm, u);
    s = 4.0f * t * r * r;
}

// Pre-split w1..w5 into fp16 hi/lo, transposed + packed in MFMA A-frag order:
// wt2[(l*2+c)*65536 + ((jt*8+kc)*64 + lane)*8 + i] = comp_c(W[k][j]),
// j = jt*16 + (lane&15), k = kc*32 + (lane>>4)*8 + i.   (16x16x32 frag order)
__global__ void prep_w_kernel(const float* __restrict__ w1, const float* __restrict__ w2,
                              const float* __restrict__ w3, const float* __restrict__ w4,
                              const float* __restrict__ w5, _Float16* __restrict__ wt2)
{
    const int idx = blockIdx.x * blockDim.x + threadIdx.x;
    if (idx >= 5 * 16 * 8 * 64) return;
    const int lane = idx & 63;
    const int kc   = (idx >> 6) & 7;
    const int jt   = (idx >> 9) & 15;
    const int l    = idx >> 13;
    const float* Wsrc[5] = { w1, w2, w3, w4, w5 };
    const float* W = Wsrc[l];
    const int j  = jt * 16 + (lane & 15);
    const int k0 = kc * 32 + (lane >> 4) * 8;
    f16x8 vh, vl;
    #pragma unroll
    for (int i = 0; i < 8; ++i) {
        _Float16 h, lo;
        split2(W[(k0 + i) * WIDTH + j], h, lo);
        vh[i] = h; vl[i] = lo;
    }
    const int fo = ((jt * 8 + kc) * 64 + lane) * 8;
    *(f16x8*)(wt2 + (l * 2 + 0) * 65536 + fo) = vh;
    *(f16x8*)(wt2 + (l * 2 + 1) * 65536 + fo) = vl;
}

// 256 threads (4 waves, 1 wave/SIMD, 1 block/CU @ 160 KiB LDS) process TWO
// 16-point groups, software-pipelined one phase apart WITHIN each wave:
// every wave's instruction stream interleaves group-X's MFMA k-loop with
// group-Y's VALU epilogue (EP chunk after every other kc, same basic block),
// so EP issues in the MFMA issue-stall gaps -> matrix and vector pipes overlap.
// Layer sequence is a RUNTIME loop (2 KLEP inline sites inside) to keep the
// emitted code size ~4x smaller than the fully-unrolled variant (compile-time
// blowup suspected in the r3/r4 container failures).
__global__ __launch_bounds__(256, 1)
void pde_mfma_kernel(const float* __restrict__ xyt,
                     const float* __restrict__ w0, const float* __restrict__ b0,
                     const float* __restrict__ b1, const float* __restrict__ b2,
                     const float* __restrict__ b3, const float* __restrict__ b4,
                     const float* __restrict__ b5,
                     const float* __restrict__ w6, const float* __restrict__ b6,
                     const _Float16* __restrict__ wt2,
                     float* __restrict__ out)
{
    __shared__ _Float16 Zs[4 * CPLANE];    // 163840 B = full LDS, two group halves

    const int tid = threadIdx.x;
    _Float16* const Zg0 = Zs;
    _Float16* const Zg1 = Zs + 2 * CPLANE;
    float* const redf0 = (float*)Zg0;      // aliased reduction scratch per group
    float* const redf1 = (float*)Zg1;
    const long gp0_0 = (long)blockIdx.x * (2 * PTS);
    const long gp0_1 = gp0_0 + PTS;

    const int lane = tid & 63;
    const int wv   = tid >> 6;       // wave 0..3 -> M-tiles 4w..4w+3
    const int q    = lane >> 4;
    const int n15  = lane & 15;

    f32x4 accA[5][4], accB[5][4];

    // ---------------- layer 0: (3 -> 256), Taylor-mode, fp32 VALU ----------
    auto L0 = [&](_Float16* Zg, long gp0) {
        const int p = tid & 15;
        const float x  = xyt[(gp0 + p) * 3 + 0];
        const float y  = xyt[(gp0 + p) * 3 + 1];
        const float tc = xyt[(gp0 + p) * 3 + 2];
        #pragma unroll
        for (int half = 0; half < 2; ++half) {
            const int jg = (tid >> 4) + half * 16;   // 0..31, 8 features each
            f16x8 vh[5], vl[5];
            #pragma unroll
            for (int c = 0; c < 8; ++c) {
                const int j = jg * 8 + c;
                const float wx = w0[0 * WIDTH + j];
                const float wy = w0[1 * WIDTH + j];
                const float wt = w0[2 * WIDTH + j];
                float zv, s;
                tanh_s(fmaf(x, wx, fmaf(y, wy, fmaf(tc, wt, b0[j]))), zv, s);
                const float vals[5] = { zv, s * wx, s * wy, s * wt,
                                        -2.0f * zv * s * (wx * wx + wy * wy) };
                #pragma unroll
                for (int v = 0; v < 5; ++v) {
                    _Float16 h, lo;
                    split2(vals[v], h, lo);
                    vh[v][c] = h; vl[v][c] = lo;
                }
            }
            #pragma unroll
            for (int v = 0; v < 5; ++v) {
                const int off = ((v * 8 + (jg >> 2)) * 64 + (jg & 3) * 16 + p) * 8;
                *(f16x8*)&Zg[0 * CPLANE + off] = vh[v];
                *(f16x8*)&Zg[1 * CPLANE + off] = vl[v];
            }
        }
    };

    // ---------------- epilogue chunk for one M-tile (4 features x 16 pts) ---
    // le is runtime: bias pointer picked via select chain (register-only).
    auto EP_Mt = [&](int le, _Float16* Zg, f32x4 (&acc)[5][4], int Mt) {
        const float* Bb = (le == 0) ? b1 : (le == 1) ? b2 : (le == 2) ? b3
                        : (le == 3) ? b4 : b5;
        const int jt = wv * 4 + Mt;
        float nv[5][4];
        #pragma unroll
        for (int reg = 0; reg < 4; ++reg) {
            const int j = jt * 16 + q * 4 + reg;
            float zv, s;
            tanh_s(acc[0][Mt][reg] + Bb[j], zv, s);
            const float u1 = acc[1][Mt][reg];
            const float u2 = acc[2][Mt][reg];
            nv[0][reg] = zv;
            nv[1][reg] = s * u1;
            nv[2][reg] = s * u2;
            nv[3][reg] = s * acc[3][Mt][reg];
            nv[4][reg] = fmaf(-2.0f * zv * s, fmaf(u1, u1, u2 * u2),
                              s * acc[4][Mt][reg]);
        }
        const int j0 = jt * 16 + q * 4;
        const int off0 = ((j0 >> 5) * 64 + ((j0 >> 3) & 3) * 16 + n15) * 8 + (j0 & 7);
        #pragma unroll
        for (int v = 0; v < 5; ++v) {
            const h16x2 h01 = __builtin_amdgcn_cvt_pkrtz(nv[v][0], nv[v][1]);
            const h16x2 h23 = __builtin_amdgcn_cvt_pkrtz(nv[v][2], nv[v][3]);
            const h16x2 l01 = __builtin_amdgcn_cvt_pkrtz(nv[v][0] - (float)h01[0],
                                                         nv[v][1] - (float)h01[1]);
            const h16x2 l23 = __builtin_amdgcn_cvt_pkrtz(nv[v][2] - (float)h23[0],
                                                         nv[v][3] - (float)h23[1]);
            *(f16x4*)&Zg[0 * CPLANE + v * 4096 + off0] =
                (f16x4){ (_Float16)h01[0], (_Float16)h01[1],
                         (_Float16)h23[0], (_Float16)h23[1] };
            *(f16x4*)&Zg[1 * CPLANE + v * 4096 + off0] =
                (f16x4){ (_Float16)l01[0], (_Float16)l01[1],
                         (_Float16)l23[0], (_Float16)l23[1] };
        }
    };

    // ------------- fused segment: K-loop(lk, ZgK->aK) + interleaved EP ------
    // kc/Mt/doEp compile-time after unroll; lk/le runtime (SGPR-only effects).
    // EP chunk for M-tile kc>>1 emitted after kc = 1,3,5,7.
    auto KLEP = [&](int lk, const _Float16* ZgK, f32x4 (&aK)[5][4],
                    int le, _Float16* ZgE, f32x4 (&aE)[5][4], bool doEp) {
        const _Float16* Wl = wt2 + lk * 2 * 65536;
        #pragma unroll
        for (int v = 0; v < 5; ++v)
            #pragma unroll
            for (int Mt = 0; Mt < 4; ++Mt)
                aK[v][Mt] = (f32x4){0.f, 0.f, 0.f, 0.f};
        #pragma unroll
        for (int kc = 0; kc < 8; ++kc) {
            f16x8 Ah[4], Al[4];
            #pragma unroll
            for (int Mt = 0; Mt < 4; ++Mt) {
                const int fo = (((wv * 4 + Mt) * 8 + kc) * 64 + lane) * 8;
                Ah[Mt] = *(const f16x8*)(Wl + fo);
                Al[Mt] = *(const f16x8*)(Wl + 65536 + fo);
            }
            #pragma unroll
            for (int v = 0; v < 5; ++v) {
                const int zo = ((v * 8 + kc) * 64 + lane) * 8;
                const f16x8 Bh = *(const f16x8*)&ZgK[0 * CPLANE + zo];
                const f16x8 Bl = *(const f16x8*)&ZgK[1 * CPLANE + zo];
                #pragma unroll
                for (int Mt = 0; Mt < 4; ++Mt) {
                    f32x4 a = aK[v][Mt];
                    a = __builtin_amdgcn_mfma_f32_16x16x32_f16(Ah[Mt], Bl, a, 0, 0, 0);
                    a = __builtin_amdgcn_mfma_f32_16x16x32_f16(Al[Mt], Bh, a, 0, 0, 0);
                    a = __builtin_amdgcn_mfma_f32_16x16x32_f16(Ah[Mt], Bh, a, 0, 0, 0);
                    aK[v][Mt] = a;
                }
            }
            if (doEp && (kc & 1)) EP_Mt(le, ZgE, aE, kc >> 1);
        }
    };

    // ---------------- final layer: (256 -> 1) dot products ------------------
    auto FDOT = [&](const _Float16* Zg) -> float {
        float partial = 0.f;
        if (tid < 2 * NROW) {
            const int n  = tid >> 1;        // row 0..79
            const int hf = tid & 1;
            const int v = n >> 4, p = n & 15;
            for (int kk = hf * 128; kk < hf * 128 + 128; kk += 8) {
                const int off = ((v * 8 + (kk >> 5)) * 64 + ((kk >> 3) & 3) * 16 + p) * 8;
                const f16x8 zh = *(const f16x8*)&Zg[0 * CPLANE + off];
                const f16x8 zl = *(const f16x8*)&Zg[1 * CPLANE + off];
                #pragma unroll
                for (int i = 0; i < 8; ++i)
                    partial = fmaf((float)zh[i] + (float)zl[i], w6[kk + i], partial);
            }
        }
        return partial;
    };
    auto RES = [&](const float* redf, long gp0) {
        if (tid < PTS) {
            const int p = tid;
            const float h   = redf[0 * 16 + p] + redf[NROW + 0 * 16 + p] + b6[0];
            const float hx  = redf[1 * 16 + p] + redf[NROW + 1 * 16 + p];
            const float hy  = redf[2 * 16 + p] + redf[NROW + 2 * 16 + p];
            const float ht  = redf[3 * 16 + p] + redf[NROW + 3 * 16 + p];
            const float lap = redf[4 * 16 + p] + redf[NROW + 4 * 16 + p];
            const float x  = xyt[(gp0 + p) * 3 + 0];
            const float y  = xyt[(gp0 + p) * 3 + 1];
            const float tc = xyt[(gp0 + p) * 3 + 2];
            const float pi = 3.14159265358979323846f;
            const float f = sinf(pi * x) * sinf(pi * y) * expf(-tc);
            out[gp0 + p] = ht - 0.5f * (fmaf(h, lap, fmaf(hx, hx, hy * hy))) - f;
        }
    };

    // ---------------- pipelined schedule ------------------------------------
    // S0:  L0(g0)
    // S1:  L0(g1)          | KL(0,g0)->accA
    // S2:  KL(0,g1)->accB  | EP(0,g0,accA)
    // S3:  KL(1,g0)->accA  | EP(0,g1,accB)
    // ...
    // S10: KL(4,g1)->accB  | EP(4,g0,accA)
    // S11: FDOT(g0)        | EP(4,g1,accB)
    // S12: FDOT(g1)        | FW(g0)
    // S13: RES(g0)         | FW(g1)
    // S14: RES(g1)
    L0(Zg0, gp0_0);
    __syncthreads();
    L0(Zg1, gp0_1);                       // global loads issue early
    KLEP(0, Zg0, accA, 0, Zg0, accB, false);   // doEp=false: ZgE unused
    __syncthreads();
    #pragma unroll 1
    for (int l = 0; l < 4; ++l) {
        KLEP(l,     Zg1, accB, l, Zg0, accA, true);
        __syncthreads();
        KLEP(l + 1, Zg0, accA, l, Zg1, accB, true);
        __syncthreads();
    }
    KLEP(4, Zg1, accB, 4, Zg0, accA, true);
    __syncthreads();

    const float pA = FDOT(Zg0);
    #pragma unroll
    for (int Mt = 0; Mt < 4; ++Mt) EP_Mt(4, Zg1, accB, Mt);
    __syncthreads();
    const float pB = FDOT(Zg1);
    if (tid < 2 * NROW) redf0[(tid & 1) * NROW + (tid >> 1)] = pA;
    __syncthreads();
    RES(redf0, gp0_0);
    if (tid < 2 * NROW) redf1[(tid & 1) * NROW + (tid >> 1)] = pB;
    __syncthreads();
    RES(redf1, gp0_1);
}

extern "C" void kernel_launch(void* const* d_in, const int* in_sizes, int n_in,
                              void* d_out, int out_size, void* d_ws, size_t ws_size,
                              hipStream_t stream) {
    const float* xyt = (const float*)d_in[0];
    const float* w0  = (const float*)d_in[1];
    const float* b0  = (const float*)d_in[2];
    const float* w1  = (const float*)d_in[3];
    const float* b1  = (const float*)d_in[4];
    const float* w2  = (const float*)d_in[5];
    const float* b2  = (const float*)d_in[6];
    const float* w3  = (const float*)d_in[7];
    const float* b3  = (const float*)d_in[8];
    const float* w4  = (const float*)d_in[9];
    const float* b4  = (const float*)d_in[10];
    const float* w5  = (const float*)d_in[11];
    const float* b5  = (const float*)d_in[12];
    const float* w6  = (const float*)d_in[13];
    const float* b6  = (const float*)d_in[14];
    float* out = (float*)d_out;
    _Float16* wt2 = (_Float16*)d_ws;    // needs 5*2*65536*2 = 1,310,720 B

    prep_w_kernel<<<160, 256, 0, stream>>>(w1, w2, w3, w4, w5, wt2);

    const int npts = in_sizes[0] / 3;   // 131072
    dim3 grid(npts / (2 * PTS));        // 4096 blocks, 2 groups each
    dim3 block(256);
    pde_mfma_kernel<<<grid, block, 0, stream>>>(xyt, w0, b0, b1, b2, b3, b4, b5,
                                                w6, b6, wt2, out);
}

// Round 6
// 795.941 us; speedup vs baseline: 1.6663x; 1.6663x over previous
//
#include <hip/hip_runtime.h>
#include <math.h>

#define WIDTH 256
#define PTS 16
#define NROW 80            // 5 chains * 16 points
#define CPLANE 20480       // halves per Z plane: 5v * 8kc * 64lane * 8

typedef _Float16 f16x8 __attribute__((ext_vector_type(8)));
typedef _Float16 f16x4 __attribute__((ext_vector_type(4)));
typedef __fp16   h16x2 __attribute__((ext_vector_type(2)));   // cvt_pkrtz return type
typedef float    f32x4 __attribute__((ext_vector_type(4)));

// fp32 -> fp16 hi + fp16 lo (2-split) -- used for WEIGHTS only (static, exact)
__device__ __forceinline__ void split2(float f, _Float16& h, _Float16& l) {
    h = (_Float16)f;
    l = (_Float16)(f - (float)h);
}
// z=tanh(u), s=1-z^2 = 4t/(1+t)^2 with t=exp(-2|u|): no cancellation in saturation.
// rcp via v_rcp_f32 (~1 ulp) instead of IEEE divide; verified absmax-neutral (r2).
__device__ __forceinline__ void tanh_s(float u, float& z, float& s) {
    const float t = __expf(-2.0f * fabsf(u));
    const float r = __builtin_amdgcn_rcpf(1.0f + t);
    const float zm = (1.0f - t) * r;
    z = copysignf(zm, u);
    s = 4.0f * t * r * r;
}

// Pre-split w1..w5 into fp16 hi/lo, transposed + packed in MFMA A-frag order:
// wt2[(l*2+c)*65536 + ((jt*8+kc)*64 + lane)*8 + i] = comp_c(W[k][j]),
// j = jt*16 + (lane&15), k = kc*32 + (lane>>4)*8 + i.   (16x16x32 frag order)
__global__ void prep_w_kernel(const float* __restrict__ w1, const float* __restrict__ w2,
                              const float* __restrict__ w3, const float* __restrict__ w4,
                              const float* __restrict__ w5, _Float16* __restrict__ wt2)
{
    const int idx = blockIdx.x * blockDim.x + threadIdx.x;
    if (idx >= 5 * 16 * 8 * 64) return;
    const int lane = idx & 63;
    const int kc   = (idx >> 6) & 7;
    const int jt   = (idx >> 9) & 15;
    const int l    = idx >> 13;
    const float* Wsrc[5] = { w1, w2, w3, w4, w5 };
    const float* W = Wsrc[l];
    const int j  = jt * 16 + (lane & 15);
    const int k0 = kc * 32 + (lane >> 4) * 8;
    f16x8 vh, vl;
    #pragma unroll
    for (int i = 0; i < 8; ++i) {
        _Float16 h, lo;
        split2(W[(k0 + i) * WIDTH + j], h, lo);
        vh[i] = h; vl[i] = lo;
    }
    const int fo = ((jt * 8 + kc) * 64 + lane) * 8;
    *(f16x8*)(wt2 + (l * 2 + 0) * 65536 + fo) = vh;
    *(f16x8*)(wt2 + (l * 2 + 1) * 65536 + fo) = vl;
}

// Round-0 structure (2 blocks/CU, in-phase): Z stored fp16-HI ONLY (one plane,
// 40 KiB/block). Weights keep exact 2-split -> 2 MFMA products per (v,Mt):
// acc += Al*Bh + Ah*Bh. MFMA pipe work is 2/3 of the 3-product scheme; EP/L0
// skip all Z-lo remainder computation and stores; FDOT reads hi only.
__global__ __launch_bounds__(256, 2)
void pde_mfma_kernel(const float* __restrict__ xyt,
                     const float* __restrict__ w0, const float* __restrict__ b0,
                     const float* __restrict__ b1, const float* __restrict__ b2,
                     const float* __restrict__ b3, const float* __restrict__ b4,
                     const float* __restrict__ b5,
                     const float* __restrict__ w6, const float* __restrict__ b6,
                     const _Float16* __restrict__ wt2,
                     float* __restrict__ out)
{
    // Zs[((v*8 + kc)*64 + lane)*8 + i] = Z[point n = lane&15, k = kc*32 + (lane>>4)*8 + i]
    __shared__ _Float16 Zs[CPLANE];   // 40960 B
    float* redf = (float*)Zs;         // aliased reduction scratch (after last Z read)

    const int tid = threadIdx.x;
    const long gp0 = (long)blockIdx.x * PTS;

    // ---------------- layer 0: (3 -> 256), Taylor-mode, fp32 VALU ----------
    {
        const int p = tid & 15;
        const float x = xyt[(gp0 + p) * 3 + 0];
        const float y = xyt[(gp0 + p) * 3 + 1];
        const float t = xyt[(gp0 + p) * 3 + 2];
        #pragma unroll
        for (int half = 0; half < 2; ++half) {
            const int jg = (tid >> 4) + half * 16;   // 0..31, 8 features each
            f16x8 vh[5];
            #pragma unroll
            for (int c = 0; c < 8; ++c) {
                const int j = jg * 8 + c;
                const float wx = w0[0 * WIDTH + j];
                const float wy = w0[1 * WIDTH + j];
                const float wt = w0[2 * WIDTH + j];
                float zv, s;
                tanh_s(fmaf(x, wx, fmaf(y, wy, fmaf(t, wt, b0[j]))), zv, s);
                const float vals[5] = { zv, s * wx, s * wy, s * wt,
                                        -2.0f * zv * s * (wx * wx + wy * wy) };
                #pragma unroll
                for (int v = 0; v < 5; ++v)
                    vh[v][c] = (_Float16)vals[v];
            }
            // j block jg*8..+7: kc = jg>>2, q' = jg&3, i = c
            #pragma unroll
            for (int v = 0; v < 5; ++v) {
                const int off = ((v * 8 + (jg >> 2)) * 64 + (jg & 3) * 16 + p) * 8;
                *(f16x8*)&Zs[off] = vh[v];
            }
        }
    }
    __syncthreads();

    // ---------------- hidden layers 1..5: MFMA fp16, weight-2-split (2 prods)
    const float* Bsl[5] = { b1, b2, b3, b4, b5 };
    const int lane = tid & 63;
    const int wv   = tid >> 6;       // wave 0..3 -> M-tiles 4w..4w+3
    const int q    = lane >> 4;
    const int n15  = lane & 15;

    for (int l = 0; l < 5; ++l) {
        const _Float16* Wl = wt2 + l * 2 * 65536;
        f32x4 acc[5][4];
        #pragma unroll
        for (int v = 0; v < 5; ++v)
            #pragma unroll
            for (int Mt = 0; Mt < 4; ++Mt)
                acc[v][Mt] = (f32x4){0.f, 0.f, 0.f, 0.f};

        #pragma unroll 2
        for (int kc = 0; kc < 8; ++kc) {
            f16x8 Ah[4], Al[4];
            #pragma unroll
            for (int Mt = 0; Mt < 4; ++Mt) {
                const int fo = (((wv * 4 + Mt) * 8 + kc) * 64 + lane) * 8;
                Ah[Mt] = *(const f16x8*)(Wl + fo);
                Al[Mt] = *(const f16x8*)(Wl + 65536 + fo);
            }
            #pragma unroll
            for (int v = 0; v < 5; ++v) {
                const int zo = ((v * 8 + kc) * 64 + lane) * 8;
                const f16x8 Bh = *(const f16x8*)&Zs[zo];
                #pragma unroll
                for (int Mt = 0; Mt < 4; ++Mt) {
                    f32x4 a = acc[v][Mt];
                    a = __builtin_amdgcn_mfma_f32_16x16x32_f16(Al[Mt], Bh, a, 0, 0, 0);
                    a = __builtin_amdgcn_mfma_f32_16x16x32_f16(Ah[Mt], Bh, a, 0, 0, 0);
                    acc[v][Mt] = a;
                }
            }
        }
        __syncthreads();   // all Zs reads done before overwrite

        // epilogue: lane holds (j = jt*16 + q*4 + reg, p = n15), all 5 chains
        const float* Bb = Bsl[l];
        #pragma unroll
        for (int Mt = 0; Mt < 4; ++Mt) {
            const int jt = wv * 4 + Mt;
            float nv[5][4];
            #pragma unroll
            for (int reg = 0; reg < 4; ++reg) {
                const int j = jt * 16 + q * 4 + reg;
                float zv, s;
                tanh_s(acc[0][Mt][reg] + Bb[j], zv, s);
                const float u1 = acc[1][Mt][reg];
                const float u2 = acc[2][Mt][reg];
                nv[0][reg] = zv;
                nv[1][reg] = s * u1;
                nv[2][reg] = s * u2;
                nv[3][reg] = s * acc[3][Mt][reg];
                nv[4][reg] = fmaf(-2.0f * zv * s, fmaf(u1, u1, u2 * u2),
                                  s * acc[4][Mt][reg]);
            }
            // j0 = jt*16 + q*4 -> kc' = j0>>5, q'' = (j0>>3)&3, i0 = j0&7
            const int j0 = jt * 16 + q * 4;
            const int off0 = ((j0 >> 5) * 64 + ((j0 >> 3) & 3) * 16 + n15) * 8 + (j0 & 7);
            #pragma unroll
            for (int v = 0; v < 5; ++v) {
                const h16x2 h01 = __builtin_amdgcn_cvt_pkrtz(nv[v][0], nv[v][1]);
                const h16x2 h23 = __builtin_amdgcn_cvt_pkrtz(nv[v][2], nv[v][3]);
                *(f16x4*)&Zs[v * 4096 + off0] =
                    (f16x4){ (_Float16)h01[0], (_Float16)h01[1],
                             (_Float16)h23[0], (_Float16)h23[1] };
            }
        }
        __syncthreads();
    }

    // ---------------- final layer: (256 -> 1) dot products ------------------
    // 80 rows x 2 halves of 128 features; 160 active threads.
    float partial = 0.f;
    const int n    = tid >> 1;        // row 0..79 (valid if tid < 160)
    const int half = tid & 1;
    if (tid < 2 * NROW) {
        const int v = n >> 4, p = n & 15;
        for (int kk = half * 128; kk < half * 128 + 128; kk += 8) {
            const int off = ((v * 8 + (kk >> 5)) * 64 + ((kk >> 3) & 3) * 16 + p) * 8;
            const f16x8 zh = *(const f16x8*)&Zs[off];
            #pragma unroll
            for (int i = 0; i < 8; ++i)
                partial = fmaf((float)zh[i], w6[kk + i], partial);
        }
    }
    __syncthreads();                 // all reads of Zs done before aliasing
    if (tid < 2 * NROW) redf[half * NROW + n] = partial;
    __syncthreads();
    if (tid < NROW) redf[2 * NROW + tid] = redf[tid] + redf[NROW + tid];
    __syncthreads();

    // ---------------- residual ----------------
    if (tid < PTS) {
        const int p = tid;
        const float* tot = redf + 2 * NROW;
        const float h   = tot[0 * 16 + p] + b6[0];
        const float hx  = tot[1 * 16 + p];
        const float hy  = tot[2 * 16 + p];
        const float ht  = tot[3 * 16 + p];
        const float lap = tot[4 * 16 + p];
        const float x = xyt[(gp0 + p) * 3 + 0];
        const float y = xyt[(gp0 + p) * 3 + 1];
        const float t = xyt[(gp0 + p) * 3 + 2];
        const float pi = 3.14159265358979323846f;
        const float f = sinf(pi * x) * sinf(pi * y) * expf(-t);
        out[gp0 + p] = ht - 0.5f * (fmaf(h, lap, fmaf(hx, hx, hy * hy))) - f;
    }
}

extern "C" void kernel_launch(void* const* d_in, const int* in_sizes, int n_in,
                              void* d_out, int out_size, void* d_ws, size_t ws_size,
                              hipStream_t stream) {
    const float* xyt = (const float*)d_in[0];
    const float* w0  = (const float*)d_in[1];
    const float* b0  = (const float*)d_in[2];
    const float* w1  = (const float*)d_in[3];
    const float* b1  = (const float*)d_in[4];
    const float* w2  = (const float*)d_in[5];
    const float* b2  = (const float*)d_in[6];
    const float* w3  = (const float*)d_in[7];
    const float* b3  = (const float*)d_in[8];
    const float* w4  = (const float*)d_in[9];
    const float* b4  = (const float*)d_in[10];
    const float* w5  = (const float*)d_in[11];
    const float* b5  = (const float*)d_in[12];
    const float* w6  = (const float*)d_in[13];
    const float* b6  = (const float*)d_in[14];
    float* out = (float*)d_out;
    _Float16* wt2 = (_Float16*)d_ws;    // needs 5*2*65536*2 = 1,310,720 B

    prep_w_kernel<<<160, 256, 0, stream>>>(w1, w2, w3, w4, w5, wt2);

    const int npts = in_sizes[0] / 3;   // 131072
    dim3 grid(npts / PTS);              // 8192
    dim3 block(256);
    pde_mfma_kernel<<<grid, block, 0, stream>>>(xyt, w0, b0, b1, b2, b3, b4, b5,
                                                w6, b6, wt2, out);
}